// Round 2
// baseline (434.509 us; speedup 1.0000x reference)
//
#include <hip/hip_runtime.h>
#include <hip/hip_bf16.h>

// Problem constants
constexpr int NV = 1024;   // vocab
constexpr int NH = 8;      // heads
constexpr int NB = 8;      // batch
constexpr int NT = 1024;   // seq len
constexpr int ND = NV * NH; // 8192 = value dim

typedef __bf16 bf16x8 __attribute__((ext_vector_type(8)));
typedef __bf16 bf16x4 __attribute__((ext_vector_type(4)));
typedef float f32x4 __attribute__((ext_vector_type(4)));

// ---------------- histogram: cnt[b][v] = #positions in batch b with token v ----
__global__ __launch_bounds__(256) void hist_kernel(const int* __restrict__ tok,
                                                   int* __restrict__ cnt) {
    int idx = blockIdx.x * 256 + threadIdx.x;   // 0 .. NB*NT-1
    int b = idx >> 10;
    int t = tok[idx];
    atomicAdd(&cnt[(b << 10) + t], 1);
}

// ---------------- W'[b][t][u] = cnt_b[u]*exp(h[t][u])/Z + (u==t), bf16 ---------
__global__ __launch_bounds__(256) void wprime_kernel(const float* __restrict__ h,
                                                     const int* __restrict__ cnt,
                                                     __bf16* __restrict__ wp) {
    int bt = blockIdx.x;                 // b*1024 + t
    int b = bt >> 10, t = bt & 1023;
    const float4* hrow = (const float4*)(h + (size_t)t * NV);
    const int4* crow = (const int4*)(cnt + (b << 10));
    float4 hv = hrow[threadIdx.x];
    int4 cv = crow[threadIdx.x];
    float e0 = __expf(hv.x) * (float)cv.x;
    float e1 = __expf(hv.y) * (float)cv.y;
    float e2 = __expf(hv.z) * (float)cv.z;
    float e3 = __expf(hv.w) * (float)cv.w;
    float s = (e0 + e1) + (e2 + e3);
#pragma unroll
    for (int off = 32; off > 0; off >>= 1) s += __shfl_down(s, off, 64);
    __shared__ float wsum[4];
    if ((threadIdx.x & 63) == 0) wsum[threadIdx.x >> 6] = s;
    __syncthreads();
    float rz = 1.0f / (wsum[0] + wsum[1] + wsum[2] + wsum[3]);
    int u0 = threadIdx.x << 2;
    float w0 = e0 * rz + (u0 + 0 == t ? 1.0f : 0.0f);
    float w1 = e1 * rz + (u0 + 1 == t ? 1.0f : 0.0f);
    float w2 = e2 * rz + (u0 + 2 == t ? 1.0f : 0.0f);
    float w3 = e3 * rz + (u0 + 3 == t ? 1.0f : 0.0f);
    bf16x4 pk = {(__bf16)w0, (__bf16)w1, (__bf16)w2, (__bf16)w3};
    *(bf16x4*)(wp + (size_t)bt * NV + u0) = pk;
}

// ---------------- vwT[d][k] = (bf16) vw[k][d]  (ND x NV) ------------------------
// 64x64 tile via LDS; bf16x8 (16B) coalesced writes, 128B per output row chunk.
__global__ __launch_bounds__(256) void tcast_kernel(const float* __restrict__ vw,
                                                    __bf16* __restrict__ vwT) {
    __shared__ float tile[64][65];
    int k0 = blockIdx.x << 6;      // 16 blocks
    int d0 = blockIdx.y << 6;      // 128 blocks
    int t = threadIdx.x;
    int kr = t >> 4;               // 0..15
    int dc = (t & 15) << 2;        // 0..60
#pragma unroll
    for (int s = 0; s < 4; ++s) {
        float4 v = *(const float4*)(vw + (size_t)(k0 + kr + 16 * s) * ND + d0 + dc);
        tile[kr + 16 * s][dc + 0] = v.x;
        tile[kr + 16 * s][dc + 1] = v.y;
        tile[kr + 16 * s][dc + 2] = v.z;
        tile[kr + 16 * s][dc + 3] = v.w;
    }
    __syncthreads();
    int dl = t >> 3;               // 0..31
    int ch = t & 7;                // 0..7
#pragma unroll
    for (int s = 0; s < 2; ++s) {
        int d = dl + 32 * s;
        bf16x8 o;
#pragma unroll
        for (int u = 0; u < 8; ++u) o[u] = (__bf16)tile[(ch << 3) + u][d];
        *(bf16x8*)(vwT + (size_t)(d0 + d) * NV + k0 + (ch << 3)) = o;
    }
}

// ---------------- GEMM: out[b][i][:] = (W'_b @ vw)[tok[b][i]][:] ----------------
// 256x256 tile, BK=64, 8 waves (2Mx4N), 128KB double-buffered LDS.
// Round-2 structure:
//  * XCD = batch, bm fastest within XCD: 32 co-resident blocks per XCD form
//    8 bn-groups x 4 bm -> each B tile L2-multicast to 4 blocks, A panel (2MB)
//    L2-resident. Cuts B re-fetch from L3 (round-1 FETCH_SIZE regression).
//  * Per K-tile: top {vmcnt(0 on stale loads) + barrier}, issue 8
//    global_load_lds for next tile (in flight across all phases), then
//    4 phases of {ds_reads -> barrier -> setprio MFMA setprio}. Read latency
//    absorbed by barrier wait; no post-MFMA barriers (waves may slide 1 phase
//    so reads of one wave overlap MFMAs of the other on the same SIMD).
// LDS swizzle: 16B chunk c of row r stored at physical chunk c ^ (r&7)
// (achieved by pre-swizzling the per-lane GLOBAL source; LDS dest stays linear).
#define GLD16(src, dst)                                                        \
    __builtin_amdgcn_global_load_lds(                                          \
        (const __attribute__((address_space(1))) void*)(src),                  \
        (__attribute__((address_space(3))) void*)(dst), 16, 0, 0)

__global__ __launch_bounds__(512, 2) void gemm_kernel(
    const __bf16* __restrict__ wp,    // [NB][NV][NV]
    const __bf16* __restrict__ vwT,   // [ND][NV]
    const int* __restrict__ tok,      // [NB][NT]
    float* __restrict__ out) {        // [NB][NT][ND]
    __shared__ __align__(16) __bf16 As[2 * 256 * 64];   // 64 KB
    __shared__ __align__(16) __bf16 Bs[2 * 256 * 64];   // 64 KB

    // XCD-aware mapping: 1024 blocks round-robin across 8 XCDs (blk&7).
    // XCD x owns batch x; within XCD, bm varies fastest (B tile 4-way reuse).
    int blk = blockIdx.x;
    int b = blk & 7;               // XCD id == batch
    int local = blk >> 3;          // 0..127 within XCD
    int bm_l = local & 3;          // fastest: M-tile within batch
    int bn = local >> 2;           // 0..31
    int i0 = bm_l << 8;            // row base within batch
    int n0 = bn << 8;
    int tid = threadIdx.x;

    // staging: per K-tile 2048 16B segs per matrix; thread t handles segs
    // t + 512*p -> row (t>>3)+64p, physical chunk t&7, source chunk pre-swizzled.
    int r0 = tid >> 3;            // 0..63
    int c0 = tid & 7;
    int cs = c0 ^ (r0 & 7);       // rows step by 64 so (r&7) const across p
    const __bf16* srcA[4];
    const __bf16* srcB[4];
#pragma unroll
    for (int p = 0; p < 4; ++p) {
        int r = r0 + 64 * p;      // 0..255
        int tk = tok[(b << 10) + i0 + r];
        srcA[p] = wp + (((size_t)(b << 10) + tk) << 10) + (cs << 3);
        srcB[p] = vwT + ((size_t)(n0 + r) << 10) + (cs << 3);
    }

    int lane = tid & 63;
    int wave = tid >> 6;
    int wm = wave >> 2, wn = wave & 3;   // 2 x 4 wave grid, each 128x64 out
    int quad = lane >> 4;
    int l15 = lane & 15;
    int offA[8], offB[4];                // kh=0 offsets; kh=1 is off ^ 32
#pragma unroll
    for (int f = 0; f < 8; ++f) {
        int m = (wm << 7) + (f << 4) + l15;
        offA[f] = (m << 6) + ((quad ^ (m & 7)) << 3);
    }
#pragma unroll
    for (int f = 0; f < 4; ++f) {
        int n = (wn << 6) + (f << 4) + l15;
        offB[f] = (n << 6) + ((quad ^ (n & 7)) << 3);
    }

    f32x4 acc[8][4];
#pragma unroll
    for (int i = 0; i < 8; ++i)
#pragma unroll
        for (int j = 0; j < 4; ++j) acc[i][j] = (f32x4){0.f, 0.f, 0.f, 0.f};

    __bf16* A0 = As;
    __bf16* A1 = As + 16384;
    __bf16* B0 = Bs;
    __bf16* B1 = Bs + 16384;

    // prologue: issue K-tile 0 into buf0 (first KSTEP's vmcnt(0)+barrier waits)
#pragma unroll
    for (int p = 0; p < 4; ++p) {
        GLD16(srcA[p], A0 + ((tid + 512 * p) << 3));
        GLD16(srcB[p], B0 + ((tid + 512 * p) << 3));
        srcA[p] += 64;
        srcB[p] += 64;
    }
    asm volatile("" ::: "memory");

// One K-tile (BK=64): wait stale loads (issued a full tile ago -> near-free),
// barrier, issue next tile's 8 loads (stay in flight across all phases),
// then 4 phases of {ds_reads -> barrier -> prio MFMA}.
#define KSTEP(Ab, Bb, An, Bn, MORE)                                            \
    {                                                                          \
        asm volatile("s_waitcnt vmcnt(0)" ::: "memory");                       \
        __builtin_amdgcn_s_barrier();                                          \
        if (MORE) {                                                            \
            _Pragma("unroll") for (int p = 0; p < 4; ++p) {                    \
                GLD16(srcA[p], (An) + ((tid + 512 * p) << 3));                 \
                GLD16(srcB[p], (Bn) + ((tid + 512 * p) << 3));                 \
                srcA[p] += 64;                                                 \
                srcB[p] += 64;                                                 \
            }                                                                  \
            asm volatile("" ::: "memory");                                     \
        }                                                                      \
        bf16x8 afr[4], bfr[4];                                                 \
        /* phase 0: kh0, fm 0..3 */                                            \
        _Pragma("unroll") for (int f = 0; f < 4; ++f) {                        \
            afr[f] = *(const bf16x8*)((Ab) + offA[f]);                         \
            bfr[f] = *(const bf16x8*)((Bb) + offB[f]);                         \
        }                                                                      \
        __builtin_amdgcn_s_barrier();                                          \
        __builtin_amdgcn_s_setprio(1);                                         \
        _Pragma("unroll") for (int i = 0; i < 4; ++i)                          \
            _Pragma("unroll") for (int j = 0; j < 4; ++j)                      \
                acc[i][j] = __builtin_amdgcn_mfma_f32_16x16x32_bf16(           \
                    afr[i], bfr[j], acc[i][j], 0, 0, 0);                       \
        __builtin_amdgcn_s_setprio(0);                                         \
        /* phase 1: kh0, fm 4..7 (reuse B regs) */                             \
        _Pragma("unroll") for (int f = 0; f < 4; ++f)                          \
            afr[f] = *(const bf16x8*)((Ab) + offA[4 + f]);                     \
        __builtin_amdgcn_s_barrier();                                          \
        __builtin_amdgcn_s_setprio(1);                                         \
        _Pragma("unroll") for (int i = 0; i < 4; ++i)                          \
            _Pragma("unroll") for (int j = 0; j < 4; ++j)                      \
                acc[4 + i][j] = __builtin_amdgcn_mfma_f32_16x16x32_bf16(       \
                    afr[i], bfr[j], acc[4 + i][j], 0, 0, 0);                   \
        __builtin_amdgcn_s_setprio(0);                                         \
        /* phase 2: kh1, fm 0..3 (source chunk q|4 -> phys offset ^32) */      \
        _Pragma("unroll") for (int f = 0; f < 4; ++f) {                        \
            afr[f] = *(const bf16x8*)((Ab) + (offA[f] ^ 32));                  \
            bfr[f] = *(const bf16x8*)((Bb) + (offB[f] ^ 32));                  \
        }                                                                      \
        __builtin_amdgcn_s_barrier();                                          \
        __builtin_amdgcn_s_setprio(1);                                         \
        _Pragma("unroll") for (int i = 0; i < 4; ++i)                          \
            _Pragma("unroll") for (int j = 0; j < 4; ++j)                      \
                acc[i][j] = __builtin_amdgcn_mfma_f32_16x16x32_bf16(           \
                    afr[i], bfr[j], acc[i][j], 0, 0, 0);                       \
        __builtin_amdgcn_s_setprio(0);                                         \
        /* phase 3: kh1, fm 4..7 */                                            \
        _Pragma("unroll") for (int f = 0; f < 4; ++f)                          \
            afr[f] = *(const bf16x8*)((Ab) + (offA[4 + f] ^ 32));              \
        __builtin_amdgcn_s_barrier();                                          \
        __builtin_amdgcn_s_setprio(1);                                         \
        _Pragma("unroll") for (int i = 0; i < 4; ++i)                          \
            _Pragma("unroll") for (int j = 0; j < 4; ++j)                      \
                acc[4 + i][j] = __builtin_amdgcn_mfma_f32_16x16x32_bf16(       \
                    afr[i], bfr[j], acc[4 + i][j], 0, 0, 0);                   \
        __builtin_amdgcn_s_setprio(0);                                         \
    }

#pragma unroll 1
    for (int it = 0; it < 8; ++it) {
        KSTEP(A0, B0, A1, B1, 1);          // even K-tile: compute buf0, stage buf1
        KSTEP(A1, B1, A0, B0, (it < 7));   // odd K-tile: compute buf1, stage buf0
    }

    // epilogue: C/D layout col=lane&15, row=quad*4+reg
    size_t outbase = (((size_t)(b << 10) + i0) << 13) + n0;
#pragma unroll
    for (int fi = 0; fi < 8; ++fi) {
#pragma unroll
        for (int fj = 0; fj < 4; ++fj) {
            int rr0 = (wm << 7) + (fi << 4) + (quad << 2);
            int cw = (wn << 6) + (fj << 4) + l15;
            float* po = out + outbase + ((size_t)rr0 << 13) + cw;
#pragma unroll
            for (int r = 0; r < 4; ++r)
                po[(size_t)r << 13] = acc[fi][fj][r];
        }
    }
}

extern "C" void kernel_launch(void* const* d_in, const int* in_sizes, int n_in,
                              void* d_out, int out_size, void* d_ws, size_t ws_size,
                              hipStream_t stream) {
    const int* tok = (const int*)d_in[0];       // [NB][NT] token ids
    const float* h = (const float*)d_in[1];     // [NV][NV]
    const float* vw = (const float*)d_in[2];    // [NV][ND]
    float* out = (float*)d_out;                 // [NB][NT][ND]

    char* ws = (char*)d_ws;
    int* cnt = (int*)ws;                                    // 32 KB
    __bf16* wp = (__bf16*)(ws + (1 << 16));                 // 16 MB
    __bf16* vwT = (__bf16*)(ws + (1 << 16) +
                            (size_t)NB * NV * NV * 2);      // 16 MB

    (void)hipMemsetAsync(cnt, 0, NB * NV * sizeof(int), stream);
    hist_kernel<<<NB * NT / 256, 256, 0, stream>>>(tok, cnt);
    wprime_kernel<<<NB * NV, 256, 0, stream>>>(h, cnt, wp);
    tcast_kernel<<<dim3(NV / 64, ND / 64), 256, 0, stream>>>(vw, vwT);
    gemm_kernel<<<NB * (NT / 256) * (ND / 256), 512, 0, stream>>>(wp, vwT, tok, out);
}

// Round 4
// 422.052 us; speedup vs baseline: 1.0295x; 1.0295x over previous
//
#include <hip/hip_runtime.h>
#include <hip/hip_bf16.h>

// Problem constants
constexpr int NV = 1024;   // vocab
constexpr int NH = 8;      // heads
constexpr int NB = 8;      // batch
constexpr int NT = 1024;   // seq len
constexpr int ND = NV * NH; // 8192 = value dim

typedef __bf16 bf16x8 __attribute__((ext_vector_type(8)));
typedef __bf16 bf16x4 __attribute__((ext_vector_type(4)));
typedef float f32x4 __attribute__((ext_vector_type(4)));

// ---------------- histogram: cnt[b][v] = #positions in batch b with token v ----
__global__ __launch_bounds__(256) void hist_kernel(const int* __restrict__ tok,
                                                   int* __restrict__ cnt) {
    int idx = blockIdx.x * 256 + threadIdx.x;   // 0 .. NB*NT-1
    int b = idx >> 10;
    int t = tok[idx];
    atomicAdd(&cnt[(b << 10) + t], 1);
}

// ---------------- W'[b][t][u] = cnt_b[u]*exp(h[t][u])/Z + (u==t), bf16 ---------
__global__ __launch_bounds__(256) void wprime_kernel(const float* __restrict__ h,
                                                     const int* __restrict__ cnt,
                                                     __bf16* __restrict__ wp) {
    int bt = blockIdx.x;                 // b*1024 + t
    int b = bt >> 10, t = bt & 1023;
    const float4* hrow = (const float4*)(h + (size_t)t * NV);
    const int4* crow = (const int4*)(cnt + (b << 10));
    float4 hv = hrow[threadIdx.x];
    int4 cv = crow[threadIdx.x];
    float e0 = __expf(hv.x) * (float)cv.x;
    float e1 = __expf(hv.y) * (float)cv.y;
    float e2 = __expf(hv.z) * (float)cv.z;
    float e3 = __expf(hv.w) * (float)cv.w;
    float s = (e0 + e1) + (e2 + e3);
#pragma unroll
    for (int off = 32; off > 0; off >>= 1) s += __shfl_down(s, off, 64);
    __shared__ float wsum[4];
    if ((threadIdx.x & 63) == 0) wsum[threadIdx.x >> 6] = s;
    __syncthreads();
    float rz = 1.0f / (wsum[0] + wsum[1] + wsum[2] + wsum[3]);
    int u0 = threadIdx.x << 2;
    float w0 = e0 * rz + (u0 + 0 == t ? 1.0f : 0.0f);
    float w1 = e1 * rz + (u0 + 1 == t ? 1.0f : 0.0f);
    float w2 = e2 * rz + (u0 + 2 == t ? 1.0f : 0.0f);
    float w3 = e3 * rz + (u0 + 3 == t ? 1.0f : 0.0f);
    bf16x4 pk = {(__bf16)w0, (__bf16)w1, (__bf16)w2, (__bf16)w3};
    *(bf16x4*)(wp + (size_t)bt * NV + u0) = pk;
}

// ---------------- vwT[d][k] = (bf16) vw[k][d]  (ND x NV) ------------------------
// 64x64 tile via LDS; bf16x8 (16B) coalesced writes, 128B per output row chunk.
__global__ __launch_bounds__(256) void tcast_kernel(const float* __restrict__ vw,
                                                    __bf16* __restrict__ vwT) {
    __shared__ float tile[64][65];
    int k0 = blockIdx.x << 6;      // 16 blocks
    int d0 = blockIdx.y << 6;      // 128 blocks
    int t = threadIdx.x;
    int kr = t >> 4;               // 0..15
    int dc = (t & 15) << 2;        // 0..60
#pragma unroll
    for (int s = 0; s < 4; ++s) {
        float4 v = *(const float4*)(vw + (size_t)(k0 + kr + 16 * s) * ND + d0 + dc);
        tile[kr + 16 * s][dc + 0] = v.x;
        tile[kr + 16 * s][dc + 1] = v.y;
        tile[kr + 16 * s][dc + 2] = v.z;
        tile[kr + 16 * s][dc + 3] = v.w;
    }
    __syncthreads();
    int dl = t >> 3;               // 0..31
    int ch = t & 7;                // 0..7
#pragma unroll
    for (int s = 0; s < 2; ++s) {
        int d = dl + 32 * s;
        bf16x8 o;
#pragma unroll
        for (int u = 0; u < 8; ++u) o[u] = (__bf16)tile[(ch << 3) + u][d];
        *(bf16x8*)(vwT + (size_t)(d0 + d) * NV + k0 + (ch << 3)) = o;
    }
}

// ---------------- GEMM: out[b][i][:] = (W'_b @ vw)[tok[b][i]][:] ----------------
// 256x256 tile, BK=64, 8 waves (2Mx4N), 128KB double-buffered LDS.
// Structure: ONE sync point per K-tile (vmcnt(0) on stale loads + s_barrier).
// The 4-phase interior has NO barriers: within a tile every ds_read targets
// the buffer staged before the tile-top barrier, and staging writes go to the
// other buffer, so intra-tile barriers were pure lockstep overhead (round-2
// counters: LDS-read bursts (~2800 cyc) and MFMA bursts (2480 cyc) alternated
// chip-wide, additive instead of overlapped). Waves now drift inside the
// tile: one wave's reads run under another's MFMAs; setprio(1) biases the
// MFMA-executing wave. Distinct per-phase register names (SSA) let the
// compiler hoist next-phase reads under current-phase MFMAs.
// Correctness of barrier-free interior: the last reads of a buffer are
// consumed by MFMAs (compiler inserts lgkmcnt waits) before the wave reaches
// the next tile-top barrier; re-staging of that buffer is issued only after
// that barrier.
// LDS swizzle: 16B chunk c of row r stored at physical chunk c ^ (r&7)
// (achieved by pre-swizzling the per-lane GLOBAL source; LDS dest linear).
#define GLD16(src, dst)                                                        \
    __builtin_amdgcn_global_load_lds(                                          \
        (const __attribute__((address_space(1))) void*)(src),                  \
        (__attribute__((address_space(3))) void*)(dst), 16, 0, 0)

__global__ __launch_bounds__(512, 2) void gemm_kernel(
    const __bf16* __restrict__ wp,    // [NB][NV][NV]
    const __bf16* __restrict__ vwT,   // [ND][NV]
    const int* __restrict__ tok,      // [NB][NT]
    float* __restrict__ out) {        // [NB][NT][ND]
    __shared__ __align__(16) __bf16 As[2 * 256 * 64];   // 64 KB
    __shared__ __align__(16) __bf16 Bs[2 * 256 * 64];   // 64 KB

    // XCD-aware mapping: blocks round-robin across 8 XCDs (blk&7).
    // XCD x owns batch x; within XCD, bm varies fastest (B tile 4-way reuse,
    // A panel wp[b] 2MB L2-resident).
    int blk = blockIdx.x;
    int b = blk & 7;               // XCD id == batch
    int local = blk >> 3;          // 0..127 within XCD
    int bm_l = local & 3;          // fastest: M-tile within batch
    int bn = local >> 2;           // 0..31
    int i0 = bm_l << 8;            // row base within batch
    int n0 = bn << 8;
    int tid = threadIdx.x;

    // staging: per K-tile 2048 16B segs per matrix; thread t handles segs
    // t + 512*p -> row (t>>3)+64p, physical chunk t&7, source chunk pre-swizzled.
    int r0 = tid >> 3;            // 0..63
    int c0 = tid & 7;
    int cs = c0 ^ (r0 & 7);       // rows step by 64 so (r&7) const across p
    const __bf16* srcA[4];
    const __bf16* srcB[4];
#pragma unroll
    for (int p = 0; p < 4; ++p) {
        int r = r0 + 64 * p;      // 0..255
        int tk = tok[(b << 10) + i0 + r];
        srcA[p] = wp + (((size_t)(b << 10) + tk) << 10) + (cs << 3);
        srcB[p] = vwT + ((size_t)(n0 + r) << 10) + (cs << 3);
    }

    int lane = tid & 63;
    int wave = tid >> 6;
    int wm = wave >> 2, wn = wave & 3;   // 2 x 4 wave grid, each 128x64 out
    int quad = lane >> 4;
    int l15 = lane & 15;
    int offA[8], offB[4];                // kh=0 offsets; kh=1 is off ^ 32
#pragma unroll
    for (int f = 0; f < 8; ++f) {
        int m = (wm << 7) + (f << 4) + l15;
        offA[f] = (m << 6) + ((quad ^ (m & 7)) << 3);
    }
#pragma unroll
    for (int f = 0; f < 4; ++f) {
        int n = (wn << 6) + (f << 4) + l15;
        offB[f] = (n << 6) + ((quad ^ (n & 7)) << 3);
    }

    f32x4 acc[8][4];
#pragma unroll
    for (int i = 0; i < 8; ++i)
#pragma unroll
        for (int j = 0; j < 4; ++j) acc[i][j] = (f32x4){0.f, 0.f, 0.f, 0.f};

    __bf16* A0 = As;
    __bf16* A1 = As + 16384;
    __bf16* B0 = Bs;
    __bf16* B1 = Bs + 16384;

    // prologue: issue K-tile 0 into buf0 (first KSTEP's vmcnt(0)+barrier waits)
#pragma unroll
    for (int p = 0; p < 4; ++p) {
        GLD16(srcA[p], A0 + ((tid + 512 * p) << 3));
        GLD16(srcB[p], B0 + ((tid + 512 * p) << 3));
        srcA[p] += 64;
        srcB[p] += 64;
    }
    asm volatile("" ::: "memory");

// One K-tile (BK=64): wait stale loads (issued a full tile ago -> near-free),
// ONE barrier, issue next tile's 8 loads (in flight across whole tile body),
// then barrier-free 4-phase interior (compiler-scheduled, setprio on MFMA).
#define KSTEP(Ab, Bb, An, Bn, MORE)                                            \
    {                                                                          \
        asm volatile("s_waitcnt vmcnt(0)" ::: "memory");                       \
        __builtin_amdgcn_s_barrier();                                          \
        if (MORE) {                                                            \
            _Pragma("unroll") for (int p = 0; p < 4; ++p) {                    \
                GLD16(srcA[p], (An) + ((tid + 512 * p) << 3));                 \
                GLD16(srcB[p], (Bn) + ((tid + 512 * p) << 3));                 \
                srcA[p] += 64;                                                 \
                srcB[p] += 64;                                                 \
            }                                                                  \
            asm volatile("" ::: "memory");                                     \
        }                                                                      \
        /* phase 0: kh0, fm 0..3 */                                            \
        bf16x8 af0[4], bf0[4];                                                 \
        _Pragma("unroll") for (int f = 0; f < 4; ++f) {                        \
            af0[f] = *(const bf16x8*)((Ab) + offA[f]);                         \
            bf0[f] = *(const bf16x8*)((Bb) + offB[f]);                         \
        }                                                                      \
        __builtin_amdgcn_s_setprio(1);                                         \
        _Pragma("unroll") for (int i = 0; i < 4; ++i)                          \
            _Pragma("unroll") for (int j = 0; j < 4; ++j)                      \
                acc[i][j] = __builtin_amdgcn_mfma_f32_16x16x32_bf16(           \
                    af0[i], bf0[j], acc[i][j], 0, 0, 0);                       \
        __builtin_amdgcn_s_setprio(0);                                         \
        /* phase 1: kh0, fm 4..7 (reuse bf0) */                                \
        bf16x8 af1[4];                                                         \
        _Pragma("unroll") for (int f = 0; f < 4; ++f)                          \
            af1[f] = *(const bf16x8*)((Ab) + offA[4 + f]);                     \
        __builtin_amdgcn_s_setprio(1);                                         \
        _Pragma("unroll") for (int i = 0; i < 4; ++i)                          \
            _Pragma("unroll") for (int j = 0; j < 4; ++j)                      \
                acc[4 + i][j] = __builtin_amdgcn_mfma_f32_16x16x32_bf16(       \
                    af1[i], bf0[j], acc[4 + i][j], 0, 0, 0);                   \
        __builtin_amdgcn_s_setprio(0);                                         \
        /* phase 2: kh1, fm 0..3 (source chunk q|4 -> phys offset ^32) */      \
        bf16x8 af2[4], bf2[4];                                                 \
        _Pragma("unroll") for (int f = 0; f < 4; ++f) {                        \
            af2[f] = *(const bf16x8*)((Ab) + (offA[f] ^ 32));                  \
            bf2[f] = *(const bf16x8*)((Bb) + (offB[f] ^ 32));                  \
        }                                                                      \
        __builtin_amdgcn_s_setprio(1);                                         \
        _Pragma("unroll") for (int i = 0; i < 4; ++i)                          \
            _Pragma("unroll") for (int j = 0; j < 4; ++j)                      \
                acc[i][j] = __builtin_amdgcn_mfma_f32_16x16x32_bf16(           \
                    af2[i], bf2[j], acc[i][j], 0, 0, 0);                       \
        __builtin_amdgcn_s_setprio(0);                                         \
        /* phase 3: kh1, fm 4..7 (reuse bf2) */                                \
        bf16x8 af3[4];                                                         \
        _Pragma("unroll") for (int f = 0; f < 4; ++f)                          \
            af3[f] = *(const bf16x8*)((Ab) + (offA[4 + f] ^ 32));              \
        __builtin_amdgcn_s_setprio(1);                                         \
        _Pragma("unroll") for (int i = 0; i < 4; ++i)                          \
            _Pragma("unroll") for (int j = 0; j < 4; ++j)                      \
                acc[4 + i][j] = __builtin_amdgcn_mfma_f32_16x16x32_bf16(       \
                    af3[i], bf2[j], acc[4 + i][j], 0, 0, 0);                   \
        __builtin_amdgcn_s_setprio(0);                                         \
    }

#pragma unroll 1
    for (int it = 0; it < 8; ++it) {
        KSTEP(A0, B0, A1, B1, 1);          // even K-tile: compute buf0, stage buf1
        KSTEP(A1, B1, A0, B0, (it < 7));   // odd K-tile: compute buf1, stage buf0
    }

    // epilogue: C/D layout col=lane&15, row=quad*4+reg
    size_t outbase = (((size_t)(b << 10) + i0) << 13) + n0;
#pragma unroll
    for (int fi = 0; fi < 8; ++fi) {
#pragma unroll
        for (int fj = 0; fj < 4; ++fj) {
            int rr0 = (wm << 7) + (fi << 4) + (quad << 2);
            int cw = (wn << 6) + (fj << 4) + l15;
            float* po = out + outbase + ((size_t)rr0 << 13) + cw;
#pragma unroll
            for (int r = 0; r < 4; ++r)
                po[(size_t)r << 13] = acc[fi][fj][r];
        }
    }
}

extern "C" void kernel_launch(void* const* d_in, const int* in_sizes, int n_in,
                              void* d_out, int out_size, void* d_ws, size_t ws_size,
                              hipStream_t stream) {
    const int* tok = (const int*)d_in[0];       // [NB][NT] token ids
    const float* h = (const float*)d_in[1];     // [NV][NV]
    const float* vw = (const float*)d_in[2];    // [NV][ND]
    float* out = (float*)d_out;                 // [NB][NT][ND]

    char* ws = (char*)d_ws;
    int* cnt = (int*)ws;                                    // 32 KB
    __bf16* wp = (__bf16*)(ws + (1 << 16));                 // 16 MB
    __bf16* vwT = (__bf16*)(ws + (1 << 16) +
                            (size_t)NB * NV * NV * 2);      // 16 MB

    (void)hipMemsetAsync(cnt, 0, NB * NV * sizeof(int), stream);
    hist_kernel<<<NB * NT / 256, 256, 0, stream>>>(tok, cnt);
    wprime_kernel<<<NB * NV, 256, 0, stream>>>(h, cnt, wp);
    tcast_kernel<<<dim3(NV / 64, ND / 64), 256, 0, stream>>>(vw, vwT);
    gemm_kernel<<<NB * (NT / 256) * (ND / 256), 512, 0, stream>>>(wp, vwT, tok, out);
}